// Round 1
// baseline (1315.872 us; speedup 1.0000x reference)
//
#include <hip/hip_runtime.h>
#include <math.h>

#define BS_TOT 32768
#define NN 30
#define HHD 8
#define GHH 16
#define LHH 64
#define SSS 512
#define BBB 64
#define RECON_SIZE (BBB*SSS*NN)   // 983040

// ---------------- K1: GAT + projection (fused) ----------------
// 16 graph instances per WG. Wave w handles instances 4w..4w+3 for the GAT
// part (lane = h*32+i), then all 256 threads do the 480->64 projection from
// LDS with W_proj staged in 96-row chunks.
#define NB 16
__global__ __launch_bounds__(256) void gat_proj_kernel(
    const float* __restrict__ x, const float* __restrict__ adj,
    const float* __restrict__ W_gat, const float* __restrict__ a_src,
    const float* __restrict__ a_dst, const float* __restrict__ W_proj,
    const float* __restrict__ b_proj, float* __restrict__ gat_seq,
    float* __restrict__ attn_out)
{
    __shared__ __align__(16) float gat[NB][480];
    __shared__ __align__(16) float wchunk[96*64];
    __shared__ float x_s[NB][32];
    __shared__ unsigned adjbits[32];

    const int t = threadIdx.x;
    const int bs_base = blockIdx.x * NB;

    // stage x rows (16 x 30)
    for (int rep = 0; rep < 2; ++rep) {
        int idx = rep*256 + t;
        int bl = idx >> 5, j = idx & 31;
        if (j < NN) x_s[bl][j] = x[(bs_base + bl)*NN + j];
    }
    // adjacency bitmasks (same for all instances)
    if (t < NN) {
        unsigned bits = 0;
        for (int j = 0; j < NN; ++j)
            if (adj[t*NN + j] != 0.0f) bits |= (1u << j);
        adjbits[t] = bits;
    }
    __syncthreads();

    const int wave = t >> 6, lane = t & 63;
    const int h = lane >> 5, i = lane & 31;
    const bool act = (i < NN);

    // per-head scalars: s_h = sum_d Wg[h,d]*a_src[h,d], t_h likewise
    float wg[HHD];
    float s_h = 0.f, t_h = 0.f;
    #pragma unroll
    for (int d = 0; d < HHD; ++d) {
        float w = W_gat[h*HHD + d];
        wg[d] = w;
        s_h += w * a_src[h*HHD + d];
        t_h += w * a_dst[h*HHD + d];
    }

    for (int r = 0; r < 4; ++r) {
        const int bl = wave*4 + r;
        const int bs = bs_base + bl;
        const unsigned bits = act ? adjbits[i & 31] : 0u;
        const float xi = act ? x_s[bl][i] : 0.f;
        const float esrc = xi * s_h;

        float m = -1e30f;
        for (int j = 0; j < NN; ++j) {
            if (bits & (1u << j)) {
                float e = esrc + x_s[bl][j] * t_h;
                e = (e >= 0.f) ? e : 0.2f * e;
                m = fmaxf(m, e);
            }
        }
        float Z = 0.f, Sx = 0.f;
        for (int j = 0; j < NN; ++j) {
            if (bits & (1u << j)) {
                float e = esrc + x_s[bl][j] * t_h;
                e = (e >= 0.f) ? e : 0.2f * e;
                float p = expf(e - m);
                Z += p;
                Sx += p * x_s[bl][j];
            }
        }
        const float wsum = Sx / Z;   // Z>0 for active lanes (self-loop)

        if (act) {
            float tmp[8];
            #pragma unroll
            for (int d = 0; d < 8; ++d) {
                float v = wsum * wg[d];
                tmp[d] = (v > 0.f) ? v : expm1f(v);
            }
            float4 v0 = make_float4(tmp[0], tmp[1], tmp[2], tmp[3]);
            float4 v1 = make_float4(tmp[4], tmp[5], tmp[6], tmp[7]);
            *(float4*)&gat[bl][i*GHH + h*HHD]     = v0;
            *(float4*)&gat[bl][i*GHH + h*HHD + 4] = v1;
        }

        // attn_last for s == S-1 (wave-uniform branch)
        if ((bs & (SSS-1)) == (SSS-1)) {
            const int b = bs >> 9;
            for (int j = 0; j < NN; ++j) {
                float a = 0.f;
                if (bits & (1u << j)) {
                    float e = esrc + x_s[bl][j] * t_h;
                    e = (e >= 0.f) ? e : 0.2f * e;
                    a = expf(e - m) / Z;
                }
                float ao = __shfl_xor(a, 32, 64);
                if (act && h == 0)
                    attn_out[b*(NN*NN) + i*NN + j] = 0.5f * (a + ao);
            }
        }
    }
    __syncthreads();

    // ---- projection: gat (16x480) @ W_proj (480x64), relu ----
    const int p = t & 63, grp = t >> 6;
    float acc0 = 0.f, acc1 = 0.f, acc2 = 0.f, acc3 = 0.f;
    for (int c = 0; c < 5; ++c) {
        #pragma unroll
        for (int rep = 0; rep < 24; ++rep)
            wchunk[rep*256 + t] = W_proj[c*6144 + rep*256 + t];
        __syncthreads();
        for (int kk = 0; kk < 96; kk += 4) {
            float4 g0 = *(const float4*)&gat[grp*4 + 0][c*96 + kk];
            float4 g1 = *(const float4*)&gat[grp*4 + 1][c*96 + kk];
            float4 g2 = *(const float4*)&gat[grp*4 + 2][c*96 + kk];
            float4 g3 = *(const float4*)&gat[grp*4 + 3][c*96 + kk];
            float w0 = wchunk[(kk+0)*64 + p];
            float w1 = wchunk[(kk+1)*64 + p];
            float w2 = wchunk[(kk+2)*64 + p];
            float w3 = wchunk[(kk+3)*64 + p];
            acc0 += g0.x*w0 + g0.y*w1 + g0.z*w2 + g0.w*w3;
            acc1 += g1.x*w0 + g1.y*w1 + g1.z*w2 + g1.w*w3;
            acc2 += g2.x*w0 + g2.y*w1 + g2.z*w2 + g2.w*w3;
            acc3 += g3.x*w0 + g3.y*w1 + g3.z*w2 + g3.w*w3;
        }
        __syncthreads();
    }
    const float bp = b_proj[p];
    gat_seq[(bs_base + grp*4 + 0)*64 + p] = fmaxf(acc0 + bp, 0.f);
    gat_seq[(bs_base + grp*4 + 1)*64 + p] = fmaxf(acc1 + bp, 0.f);
    gat_seq[(bs_base + grp*4 + 2)*64 + p] = fmaxf(acc2 + bp, 0.f);
    gat_seq[(bs_base + grp*4 + 3)*64 + p] = fmaxf(acc3 + bp, 0.f);
}

// ---------------- K2: one LSTM layer, one WG per batch element ----------------
// Thread g owns gate g: W_ih row + W_hh row in registers (128 VGPRs).
// Per step: gates = b + x_t.Wih_g + h.Whh_g (LDS float4 broadcasts), sigmoid/tanh,
// then lanes 0..63 update c,h. Two barriers per step.
__global__ __launch_bounds__(256) void lstm_layer_kernel(
    const float* __restrict__ xin, const float* __restrict__ W_ih,
    const float* __restrict__ W_hh, const float* __restrict__ b_ih,
    const float* __restrict__ b_hh, float* __restrict__ h_out)
{
    __shared__ __align__(16) float xh[128];   // [0:64]=x_t, [64:128]=h
    __shared__ float gates[256];

    const int g = threadIdx.x;
    const int b = blockIdx.x;

    float wih[64], whh[64];
    #pragma unroll
    for (int k4 = 0; k4 < 16; ++k4) {
        float4 a = *(const float4*)&W_ih[g*64 + k4*4];
        float4 c4 = *(const float4*)&W_hh[g*64 + k4*4];
        wih[k4*4+0] = a.x;  wih[k4*4+1] = a.y;  wih[k4*4+2] = a.z;  wih[k4*4+3] = a.w;
        whh[k4*4+0] = c4.x; whh[k4*4+1] = c4.y; whh[k4*4+2] = c4.z; whh[k4*4+3] = c4.w;
    }
    const float bsum = b_ih[g] + b_hh[g];
    float c = 0.f;
    if (g < 64) xh[64 + g] = 0.f;

    const float* xrow = xin + (size_t)b * SSS * 64;
    float* hrow = h_out + (size_t)b * SSS * 64;

    for (int tt = 0; tt < SSS; ++tt) {
        if (g < 64) xh[g] = xrow[tt*64 + g];
        __syncthreads();

        float acc = bsum;
        #pragma unroll
        for (int k4 = 0; k4 < 16; ++k4) {
            float4 xv = *(const float4*)&xh[k4*4];
            float4 hv = *(const float4*)&xh[64 + k4*4];
            acc += xv.x*wih[k4*4+0] + xv.y*wih[k4*4+1]
                 + xv.z*wih[k4*4+2] + xv.w*wih[k4*4+3];
            acc += hv.x*whh[k4*4+0] + hv.y*whh[k4*4+1]
                 + hv.z*whh[k4*4+2] + hv.w*whh[k4*4+3];
        }
        const int sect = g >> 6;
        float a = (sect == 2) ? tanhf(acc) : (1.f / (1.f + expf(-acc)));
        gates[g] = a;
        __syncthreads();

        if (g < 64) {
            float ig = gates[g], fg = gates[64+g], gg = gates[128+g], og = gates[192+g];
            c = fg*c + ig*gg;
            float h = og * tanhf(c);
            xh[64 + g] = h;
            hrow[tt*64 + g] = h;
        }
    }
}

// ---------------- K3: recon = h2 @ W_out + b_out ----------------
__global__ __launch_bounds__(256) void recon_kernel(
    const float* __restrict__ h2, const float* __restrict__ W_out,
    const float* __restrict__ b_out, float* __restrict__ out)
{
    __shared__ __align__(16) float hl[8*64];
    const int t = threadIdx.x;
    const int bs_base = blockIdx.x * 8;

    hl[t]       = h2[(size_t)bs_base*64 + t];
    hl[256 + t] = h2[(size_t)bs_base*64 + 256 + t];
    __syncthreads();

    if (t < 240) {
        const int bl = t / 30;
        const int n  = t - bl*30;
        float acc = b_out[n];
        #pragma unroll
        for (int k = 0; k < 64; ++k)
            acc += hl[bl*64 + k] * W_out[k*NN + n];
        out[(size_t)(bs_base + bl)*NN + n] = acc;
    }
}

extern "C" void kernel_launch(void* const* d_in, const int* in_sizes, int n_in,
                              void* d_out, int out_size, void* d_ws, size_t ws_size,
                              hipStream_t stream)
{
    const float* x      = (const float*)d_in[0];
    const float* adj    = (const float*)d_in[1];
    const float* W_gat  = (const float*)d_in[2];
    const float* a_src  = (const float*)d_in[3];
    const float* a_dst  = (const float*)d_in[4];
    const float* W_proj = (const float*)d_in[5];
    const float* b_proj = (const float*)d_in[6];
    const float* W_ih0  = (const float*)d_in[7];
    const float* W_hh0  = (const float*)d_in[8];
    const float* b_ih0  = (const float*)d_in[9];
    const float* b_hh0  = (const float*)d_in[10];
    const float* W_ih1  = (const float*)d_in[11];
    const float* W_hh1  = (const float*)d_in[12];
    const float* b_ih1  = (const float*)d_in[13];
    const float* b_hh1  = (const float*)d_in[14];
    const float* W_out  = (const float*)d_in[15];
    const float* b_out  = (const float*)d_in[16];

    float* out = (float*)d_out;
    float* gat_seq = (float*)d_ws;                 //  8.4 MB
    float* h1 = gat_seq + (size_t)BS_TOT*64;       //  8.4 MB
    float* h2 = h1 + (size_t)BS_TOT*64;            //  8.4 MB

    hipLaunchKernelGGL(gat_proj_kernel, dim3(BS_TOT/NB), dim3(256), 0, stream,
                       x, adj, W_gat, a_src, a_dst, W_proj, b_proj,
                       gat_seq, out + RECON_SIZE);
    hipLaunchKernelGGL(lstm_layer_kernel, dim3(BBB), dim3(256), 0, stream,
                       gat_seq, W_ih0, W_hh0, b_ih0, b_hh0, h1);
    hipLaunchKernelGGL(lstm_layer_kernel, dim3(BBB), dim3(256), 0, stream,
                       h1, W_ih1, W_hh1, b_ih1, b_hh1, h2);
    hipLaunchKernelGGL(recon_kernel, dim3(BS_TOT/8), dim3(256), 0, stream,
                       h2, W_out, b_out, out);
}

// Round 2
// 733.607 us; speedup vs baseline: 1.7937x; 1.7937x over previous
//
#include <hip/hip_runtime.h>
#include <math.h>

#define BS_TOT 32768
#define NN 30
#define HHD 8
#define GHH 16
#define LHH 64
#define SSS 512
#define BBB 64
#define RECON_SIZE (BBB*SSS*NN)   // 983040

__device__ __forceinline__ float fsigmoid(float x) {
    return 1.f / (1.f + __expf(-x));
}
__device__ __forceinline__ float ftanh(float x) {
    float ax = fabsf(x);
    float e = __expf(-2.f * ax);
    float r = (1.f - e) / (1.f + e);
    return copysignf(r, x);
}

// ---------------- K1: GAT + projection (fused) ----------------
#define NB 16
__global__ __launch_bounds__(256) void gat_proj_kernel(
    const float* __restrict__ x, const float* __restrict__ adj,
    const float* __restrict__ W_gat, const float* __restrict__ a_src,
    const float* __restrict__ a_dst, const float* __restrict__ W_proj,
    const float* __restrict__ b_proj, float* __restrict__ gat_seq,
    float* __restrict__ attn_out)
{
    __shared__ __align__(16) float gat[NB][480];
    __shared__ __align__(16) float wchunk[96*64];
    __shared__ float x_s[NB][32];
    __shared__ unsigned adjbits[32];

    const int t = threadIdx.x;
    const int bs_base = blockIdx.x * NB;

    for (int rep = 0; rep < 2; ++rep) {
        int idx = rep*256 + t;
        int bl = idx >> 5, j = idx & 31;
        if (j < NN) x_s[bl][j] = x[(bs_base + bl)*NN + j];
    }
    if (t < NN) {
        unsigned bits = 0;
        for (int j = 0; j < NN; ++j)
            if (adj[t*NN + j] != 0.0f) bits |= (1u << j);
        adjbits[t] = bits;
    }
    __syncthreads();

    const int wave = t >> 6, lane = t & 63;
    const int h = lane >> 5, i = lane & 31;
    const bool act = (i < NN);

    float wg[HHD];
    float s_h = 0.f, t_h = 0.f;
    #pragma unroll
    for (int d = 0; d < HHD; ++d) {
        float w = W_gat[h*HHD + d];
        wg[d] = w;
        s_h += w * a_src[h*HHD + d];
        t_h += w * a_dst[h*HHD + d];
    }

    for (int r = 0; r < 4; ++r) {
        const int bl = wave*4 + r;
        const int bs = bs_base + bl;
        const unsigned bits = act ? adjbits[i & 31] : 0u;
        const float xi = act ? x_s[bl][i] : 0.f;
        const float esrc = xi * s_h;

        float m = -1e30f;
        for (int j = 0; j < NN; ++j) {
            if (bits & (1u << j)) {
                float e = esrc + x_s[bl][j] * t_h;
                e = (e >= 0.f) ? e : 0.2f * e;
                m = fmaxf(m, e);
            }
        }
        float Z = 0.f, Sx = 0.f;
        for (int j = 0; j < NN; ++j) {
            if (bits & (1u << j)) {
                float e = esrc + x_s[bl][j] * t_h;
                e = (e >= 0.f) ? e : 0.2f * e;
                float p = expf(e - m);
                Z += p;
                Sx += p * x_s[bl][j];
            }
        }
        const float wsum = Sx / Z;

        if (act) {
            float tmp[8];
            #pragma unroll
            for (int d = 0; d < 8; ++d) {
                float v = wsum * wg[d];
                tmp[d] = (v > 0.f) ? v : expm1f(v);
            }
            float4 v0 = make_float4(tmp[0], tmp[1], tmp[2], tmp[3]);
            float4 v1 = make_float4(tmp[4], tmp[5], tmp[6], tmp[7]);
            *(float4*)&gat[bl][i*GHH + h*HHD]     = v0;
            *(float4*)&gat[bl][i*GHH + h*HHD + 4] = v1;
        }

        if ((bs & (SSS-1)) == (SSS-1)) {
            const int b = bs >> 9;
            for (int j = 0; j < NN; ++j) {
                float a = 0.f;
                if (bits & (1u << j)) {
                    float e = esrc + x_s[bl][j] * t_h;
                    e = (e >= 0.f) ? e : 0.2f * e;
                    a = expf(e - m) / Z;
                }
                float ao = __shfl_xor(a, 32, 64);
                if (act && h == 0)
                    attn_out[b*(NN*NN) + i*NN + j] = 0.5f * (a + ao);
            }
        }
    }
    __syncthreads();

    const int p = t & 63, grp = t >> 6;
    float acc0 = 0.f, acc1 = 0.f, acc2 = 0.f, acc3 = 0.f;
    for (int c = 0; c < 5; ++c) {
        #pragma unroll
        for (int rep = 0; rep < 24; ++rep)
            wchunk[rep*256 + t] = W_proj[c*6144 + rep*256 + t];
        __syncthreads();
        for (int kk = 0; kk < 96; kk += 4) {
            float4 g0 = *(const float4*)&gat[grp*4 + 0][c*96 + kk];
            float4 g1 = *(const float4*)&gat[grp*4 + 1][c*96 + kk];
            float4 g2 = *(const float4*)&gat[grp*4 + 2][c*96 + kk];
            float4 g3 = *(const float4*)&gat[grp*4 + 3][c*96 + kk];
            float w0 = wchunk[(kk+0)*64 + p];
            float w1 = wchunk[(kk+1)*64 + p];
            float w2 = wchunk[(kk+2)*64 + p];
            float w3 = wchunk[(kk+3)*64 + p];
            acc0 += g0.x*w0 + g0.y*w1 + g0.z*w2 + g0.w*w3;
            acc1 += g1.x*w0 + g1.y*w1 + g1.z*w2 + g1.w*w3;
            acc2 += g2.x*w0 + g2.y*w1 + g2.z*w2 + g2.w*w3;
            acc3 += g3.x*w0 + g3.y*w1 + g3.z*w2 + g3.w*w3;
        }
        __syncthreads();
    }
    const float bp = b_proj[p];
    gat_seq[(bs_base + grp*4 + 0)*64 + p] = fmaxf(acc0 + bp, 0.f);
    gat_seq[(bs_base + grp*4 + 1)*64 + p] = fmaxf(acc1 + bp, 0.f);
    gat_seq[(bs_base + grp*4 + 2)*64 + p] = fmaxf(acc2 + bp, 0.f);
    gat_seq[(bs_base + grp*4 + 3)*64 + p] = fmaxf(acc3 + bp, 0.f);
}

// ---------------- K2: fused 2-layer LSTM, pipelined ----------------
// 512 threads: t<256 -> layer0 gate t; t>=256 -> layer1 gate t-256.
// Layer1 processes step tt-1 while layer0 processes step tt.
// Weights live in 32 named float4 registers per thread.
__global__ __launch_bounds__(512) void lstm_fused_kernel(
    const float* __restrict__ xin,
    const float* __restrict__ W_ih0, const float* __restrict__ W_hh0,
    const float* __restrict__ b_ih0, const float* __restrict__ b_hh0,
    const float* __restrict__ W_ih1, const float* __restrict__ W_hh1,
    const float* __restrict__ b_ih1, const float* __restrict__ b_hh1,
    float* __restrict__ h2_out)
{
    __shared__ __align__(16) float xh[2][128];   // [l][0:64]=input_t, [l][64:128]=h state
    __shared__ float gates[512];

    const int t = threadIdx.x;
    const int b = blockIdx.x;
    const int layer = t >> 8;
    const int g = t & 255;

    const float* __restrict__ Wih = layer ? W_ih1 : W_ih0;
    const float* __restrict__ Whh = layer ? W_hh1 : W_hh0;
    const float bsum = layer ? (b_ih1[g] + b_hh1[g]) : (b_ih0[g] + b_hh0[g]);

    const float* wihp = Wih + g*64;
    const float* whhp = Whh + g*64;

#define LOADW(i) \
    const float4 wi##i = *(const float4*)(wihp + 4*(i)); \
    const float4 wh##i = *(const float4*)(whhp + 4*(i));
    LOADW(0)  LOADW(1)  LOADW(2)  LOADW(3)
    LOADW(4)  LOADW(5)  LOADW(6)  LOADW(7)
    LOADW(8)  LOADW(9)  LOADW(10) LOADW(11)
    LOADW(12) LOADW(13) LOADW(14) LOADW(15)
#undef LOADW

    // init LDS state
    if (t < 128) xh[1][t] = 0.f;
    else if (t < 192) xh[0][64 + (t - 128)] = 0.f;

    const float* __restrict__ xrow = xin + (size_t)b * SSS * 64;
    float* __restrict__ hrow = h2_out + (size_t)b * SSS * 64;

    const int sect = g >> 6;           // 0:i 1:f 2:g 3:o (wave-uniform)
    float c = 0.f;
    float xreg = (t < 64) ? xrow[t] : 0.f;

    const float* xb = &xh[layer][0];

    for (int tt = 0; tt <= SSS; ++tt) {
        if (t < 64 && tt < SSS) xh[0][t] = xreg;
        __syncthreads();
        if (t < 64 && tt + 1 < SSS) xreg = xrow[(tt+1)*64 + t];

        float s0=0.f,s1=0.f,s2=0.f,s3=0.f,s4=0.f,s5=0.f,s6=0.f,s7=0.f;
#define STEPX(i, S) { float4 v = *(const float4*)(xb + 4*(i)); \
        S = fmaf(v.x, wi##i.x, S); S = fmaf(v.y, wi##i.y, S); \
        S = fmaf(v.z, wi##i.z, S); S = fmaf(v.w, wi##i.w, S); }
#define STEPH(i, S) { float4 v = *(const float4*)(xb + 64 + 4*(i)); \
        S = fmaf(v.x, wh##i.x, S); S = fmaf(v.y, wh##i.y, S); \
        S = fmaf(v.z, wh##i.z, S); S = fmaf(v.w, wh##i.w, S); }
        STEPX(0,s0)  STEPX(1,s1)  STEPX(2,s2)  STEPX(3,s3)
        STEPX(4,s4)  STEPX(5,s5)  STEPX(6,s6)  STEPX(7,s7)
        STEPX(8,s0)  STEPX(9,s1)  STEPX(10,s2) STEPX(11,s3)
        STEPX(12,s4) STEPX(13,s5) STEPX(14,s6) STEPX(15,s7)
        STEPH(0,s0)  STEPH(1,s1)  STEPH(2,s2)  STEPH(3,s3)
        STEPH(4,s4)  STEPH(5,s5)  STEPH(6,s6)  STEPH(7,s7)
        STEPH(8,s0)  STEPH(9,s1)  STEPH(10,s2) STEPH(11,s3)
        STEPH(12,s4) STEPH(13,s5) STEPH(14,s6) STEPH(15,s7)
#undef STEPX
#undef STEPH
        float acc = bsum + (((s0+s1)+(s2+s3)) + ((s4+s5)+(s6+s7)));
        float a = (sect == 2) ? ftanh(acc) : fsigmoid(acc);
        gates[t] = a;
        __syncthreads();

        if (t < 64) {
            if (tt < SSS) {
                float ig = gates[t], fg = gates[64+t], gg = gates[128+t], og = gates[192+t];
                c = fg*c + ig*gg;
                float hv = og * ftanh(c);
                xh[0][64+t] = hv;    // h0 state for step tt+1
                xh[1][t]    = hv;    // pipe: layer1 input for step tt
            }
        } else if (t >= 256 && t < 320) {
            if (tt >= 1) {
                int u = t - 256;
                float ig = gates[256+u], fg = gates[320+u], gg = gates[384+u], og = gates[448+u];
                c = fg*c + ig*gg;
                float hv = og * ftanh(c);
                xh[1][64+u] = hv;
                hrow[(size_t)(tt-1)*64 + u] = hv;
            }
        }
    }
}

// ---------------- K3: recon = h2 @ W_out + b_out ----------------
__global__ __launch_bounds__(256) void recon_kernel(
    const float* __restrict__ h2, const float* __restrict__ W_out,
    const float* __restrict__ b_out, float* __restrict__ out)
{
    __shared__ __align__(16) float hl[8*64];
    const int t = threadIdx.x;
    const int bs_base = blockIdx.x * 8;

    hl[t]       = h2[(size_t)bs_base*64 + t];
    hl[256 + t] = h2[(size_t)bs_base*64 + 256 + t];
    __syncthreads();

    if (t < 240) {
        const int bl = t / 30;
        const int n  = t - bl*30;
        float acc = b_out[n];
        #pragma unroll
        for (int k = 0; k < 64; ++k)
            acc += hl[bl*64 + k] * W_out[k*NN + n];
        out[(size_t)(bs_base + bl)*NN + n] = acc;
    }
}

extern "C" void kernel_launch(void* const* d_in, const int* in_sizes, int n_in,
                              void* d_out, int out_size, void* d_ws, size_t ws_size,
                              hipStream_t stream)
{
    const float* x      = (const float*)d_in[0];
    const float* adj    = (const float*)d_in[1];
    const float* W_gat  = (const float*)d_in[2];
    const float* a_src  = (const float*)d_in[3];
    const float* a_dst  = (const float*)d_in[4];
    const float* W_proj = (const float*)d_in[5];
    const float* b_proj = (const float*)d_in[6];
    const float* W_ih0  = (const float*)d_in[7];
    const float* W_hh0  = (const float*)d_in[8];
    const float* b_ih0  = (const float*)d_in[9];
    const float* b_hh0  = (const float*)d_in[10];
    const float* W_ih1  = (const float*)d_in[11];
    const float* W_hh1  = (const float*)d_in[12];
    const float* b_ih1  = (const float*)d_in[13];
    const float* b_hh1  = (const float*)d_in[14];
    const float* W_out  = (const float*)d_in[15];
    const float* b_out  = (const float*)d_in[16];

    float* out = (float*)d_out;
    float* gat_seq = (float*)d_ws;                 //  8.4 MB
    float* h2 = gat_seq + (size_t)BS_TOT*64;       //  8.4 MB

    hipLaunchKernelGGL(gat_proj_kernel, dim3(BS_TOT/NB), dim3(256), 0, stream,
                       x, adj, W_gat, a_src, a_dst, W_proj, b_proj,
                       gat_seq, out + RECON_SIZE);
    hipLaunchKernelGGL(lstm_fused_kernel, dim3(BBB), dim3(512), 0, stream,
                       gat_seq, W_ih0, W_hh0, b_ih0, b_hh0,
                       W_ih1, W_hh1, b_ih1, b_hh1, h2);
    hipLaunchKernelGGL(recon_kernel, dim3(BS_TOT/8), dim3(256), 0, stream,
                       h2, W_out, b_out, out);
}